// Round 12
// baseline (869692.676 us; speedup 1.0000x reference)
//
#include <hip/hip_runtime.h>
#include <hip/hip_bf16.h>

#define SEQ  512
#define HID  1024
#define G4   4096
#define NBLK 128   // blocks per layer; grid = 256

typedef short bf16x8 __attribute__((ext_vector_type(8)));
typedef float f32x4  __attribute__((ext_vector_type(4)));
typedef float f32x2  __attribute__((ext_vector_type(2)));
typedef unsigned short usx4 __attribute__((ext_vector_type(4)));
typedef unsigned long long u64;

static __device__ __forceinline__ unsigned short f2b(float f) {
  union { float f; unsigned u; } v; v.f = f;
  unsigned r = (v.u + 0x7FFFu + ((v.u >> 16) & 1u)) >> 16;  // RNE
  return (unsigned short)r;
}

// x (B,S,I) f32 -> xb row-major (S*B, I) bf16, row r = s*64+b
__global__ __launch_bounds__(256) void k_castx(const float* __restrict__ x,
                                               unsigned short* __restrict__ xb) {
  int idx = blockIdx.x * 256 + threadIdx.x;
  int r = idx >> 8, kq = idx & 255;
  int b = r & 63, s = r >> 6;
  const f32x4* src = reinterpret_cast<const f32x4*>(x + ((size_t)b * SEQ + s) * HID + (size_t)kq * 4);
  f32x4 v = __builtin_nontemporal_load(src);
  usx4 o;
  o.x = f2b(v.x); o.y = f2b(v.y); o.z = f2b(v.z); o.w = f2b(v.w);
  *reinterpret_cast<usx4*>(xb + (size_t)r * HID + kq * 4) = o;
}

// W (K=1024, N=4096) f32 -> WT (N=4096, K=1024) bf16
__global__ __launch_bounds__(256) void k_wtrans(const float* __restrict__ W,
                                                unsigned short* __restrict__ WT) {
  __shared__ float tls[32][33];
  int tile = blockIdx.x;
  int nt = tile & 127, kt = tile >> 7;
  int tx = threadIdx.x & 31, ty = threadIdx.x >> 5;
  int k0 = kt * 32, n0 = nt * 32;
  for (int i = 0; i < 4; ++i)
    tls[ty + 8 * i][tx] = W[(size_t)(k0 + ty + 8 * i) * G4 + n0 + tx];
  __syncthreads();
  for (int i = 0; i < 4; ++i)
    WT[(size_t)(n0 + ty + 8 * i) * HID + k0 + tx] = f2b(tls[tx][ty + 8 * i]);
}

static __device__ __forceinline__ u64 gld(const u64* p) {
  return __hip_atomic_load(p, __ATOMIC_RELAXED, __HIP_MEMORY_SCOPE_AGENT);
}

// Poll 512 per-(h-wave,block) flag words (128B apart, single-writer, no RMW).
static __device__ __forceinline__ void poll_flags512(unsigned* flags, unsigned tgt) {
  const int l = threadIdx.x & 63;
  long sp = 0;
  for (;;) {
    bool ok = true;
#pragma unroll
    for (int wr = 0; wr < 4; ++wr) {
      unsigned v0 = __hip_atomic_load(flags + (wr * 128 + l) * 32,
                                      __ATOMIC_RELAXED, __HIP_MEMORY_SCOPE_AGENT);
      unsigned v1 = __hip_atomic_load(flags + (wr * 128 + 64 + l) * 32,
                                      __ATOMIC_RELAXED, __HIP_MEMORY_SCOPE_AGENT);
      ok &= (v0 >= tgt) & (v1 >= tgt);
    }
    if (__all(ok)) break;
    if (++sp > 2000000L) break;   // bailout: wrong answer beats a hang
    __builtin_amdgcn_s_sleep(1);
  }
  asm volatile("" ::: "memory");
}

static __device__ __forceinline__ void lds_wait_u(unsigned* f, unsigned tgt) {
  long sp = 0;
  while (__hip_atomic_load(f, __ATOMIC_ACQUIRE, __HIP_MEMORY_SCOPE_WORKGROUP) < tgt) {
    if (++sp > 100000000L) break;
  }
  asm volatile("" ::: "memory");
}
static __device__ __forceinline__ void seq_pub(unsigned* p, unsigned v, int lane) {
  asm volatile("s_waitcnt lgkmcnt(0)" ::: "memory");   // prior LDS ops done
  if (lane == 0)
    __hip_atomic_store(p, v, __ATOMIC_RELAXED, __HIP_MEMORY_SCOPE_WORKGROUP);
}

// r12: one-visibility-hop h exchange. Rings poisoned 0xFF per launch; valid h
// (|h|<=1) can never be bf16 0xFFFF, so a u32 half == 0xFFFFFFFF marks "not
// yet written". Producers store h with NO drain and NO flag; recurrence
// consumers poll the data itself (64 coalesced u64 agent loads, poison-check,
// selective retry). L1's x-waves (2.5 steps slack) use L2-cached plain loads
// gated by drain-free lazy per-wave flags (safe: a wave's step-t canary load
// waits retire its step t-1 stores first — vmcnt is in-order).
__global__ __launch_bounds__(512, 1) void k_scan2(
    const unsigned short* __restrict__ xb,
    const unsigned short* __restrict__ WxT0, const unsigned short* __restrict__ WhT0,
    const float* __restrict__ b0,
    const unsigned short* __restrict__ WxT1, const unsigned short* __restrict__ WhT1,
    const float* __restrict__ b1,
    unsigned short* __restrict__ h1,
    unsigned short* __restrict__ h2,
    float* __restrict__ out,
    unsigned* __restrict__ flags) {
  __shared__ unsigned short wlds[32 * 2048];   // 128 KB weights [c][k], swizzled
  __shared__ float x_lds[2][4][8][64];         // x-partials in raw MFMA layout
  __shared__ unsigned xseq[4], hseq[4];
  __shared__ unsigned xrdy;

  const int bk  = blockIdx.x;
  const int layer = bk >> 7;
  const int nb  = bk & 127;
  const int tid = threadIdx.x;
  const int w   = tid >> 6;
  const int l   = tid & 63;
  const int lq  = l >> 4, lr = l & 15;
  const int rt  = w & 3;
  const bool is_h = (w >= 4);

  const unsigned short* WxT = layer ? WxT1 : WxT0;
  const unsigned short* WhT = layer ? WhT1 : WhT0;
  const float* bias = layer ? b1 : b0;
  const unsigned short* aseq = layer ? h1 : xb;   // x-wave input rows (plain loads)
  unsigned short* hout = layer ? h2 : h1;          // ring this layer writes

  float* fout = layer ? out : nullptr;

  if (tid < 4) { xseq[tid] = 0; hseq[tid] = 0; }
  if (tid == 4) xrdy = 0;

  // ---- one-time: stage weight slice into LDS (swizzled byte addr) ----
  {
    int c = tid >> 4, seg = tid & 15;
    int gate = c >> 3, nl = c & 7;
    int gcol = gate * 1024 + nb * 8 + nl;
    const unsigned short* sx = WxT + (size_t)gcol * HID;
    const unsigned short* sh = WhT + (size_t)gcol * HID;
    for (int j = 0; j < 16; ++j) {
      int kk = seg * 128 + j * 8;
      const unsigned short* src = (kk < 1024) ? (sx + kk) : (sh + kk - 1024);
      uint4 v = *reinterpret_cast<const uint4*>(src);
      int db = (c * 4096 + kk * 2) ^ ((c & 7) << 4);
      *reinterpret_cast<uint4*>(reinterpret_cast<char*>(wlds) + db) = v;
    }
  }

  char* wbase = reinterpret_cast<char*>(wlds);
  const int csw = (lr & 7) << 4;
  const int cb0 = (lr) * 4096 + lq * 16;
  const int cb1 = (16 + lr) * 4096 + lq * 16;

  float bias_c[2];
#pragma unroll
  for (int ct = 0; ct < 2; ++ct) {
    int col = ct * 16 + lr;
    bias_c[ct] = bias[(col >> 3) * 1024 + nb * 8 + (col & 7)];
  }

  float cst[4] = {0.f, 0.f, 0.f, 0.f};   // c-state: 4 rows x 1 col per lane

  __syncthreads();
  if (is_h) __builtin_amdgcn_s_setprio(1);

  if (!is_h) {
    // ================= x-waves =================
    auto project = [&](int tt, int bufn) {
      const bf16x8* ax = reinterpret_cast<const bf16x8*>(aseq)
                         + ((size_t)tt * 64 + rt * 16 + lr) * 128 + lq;
      f32x4 acc[2][4] = {};
#pragma unroll 8
      for (int ks = 0; ks < 32; ++ks) {
        bf16x8 a  = ax[ks * 4];
        bf16x8 bb0 = *reinterpret_cast<const bf16x8*>(wbase + ((cb0 + ks * 64) ^ csw));
        bf16x8 bb1 = *reinterpret_cast<const bf16x8*>(wbase + ((cb1 + ks * 64) ^ csw));
        acc[0][ks & 3] = __builtin_amdgcn_mfma_f32_16x16x32_bf16(a, bb0, acc[0][ks & 3], 0, 0, 0);
        acc[1][ks & 3] = __builtin_amdgcn_mfma_f32_16x16x32_bf16(a, bb1, acc[1][ks & 3], 0, 0, 0);
      }
#pragma unroll
      for (int ct = 0; ct < 2; ++ct) {
        f32x4 s = (acc[ct][0] + acc[ct][1]) + (acc[ct][2] + acc[ct][3]);
        float bc = bias_c[ct];
        x_lds[bufn][w][ct * 4 + 0][l] = s.x + bc;
        x_lds[bufn][w][ct * 4 + 1][l] = s.y + bc;
        x_lds[bufn][w][ct * 4 + 2][l] = s.z + bc;
        x_lds[bufn][w][ct * 4 + 3][l] = s.w + bc;
      }
    };

    // prologue: step 0 into buf0 (L1: wait until h1[0] surely visible)
    if (layer) poll_flags512(flags, 1u);
    project(0, 0);
    seq_pub(&xseq[rt], 1u, l);

    for (int t = 0; t + 1 < SEQ; ++t) {
      if (layer) {
        if (w == 0) {
          poll_flags512(flags, (unsigned)(t + 2));   // h1[t+1] visible
          __hip_atomic_store(&xrdy, (unsigned)(t + 1), __ATOMIC_RELAXED,
                             __HIP_MEMORY_SCOPE_WORKGROUP);
        } else {
          lds_wait_u(&xrdy, (unsigned)(t + 1));
        }
      }
      lds_wait_u(&hseq[rt], (unsigned)t);   // pair h-wave done with this buffer
      project(t + 1, (t + 1) & 1);
      seq_pub(&xseq[rt], (unsigned)(t + 2), l);
    }
  } else {
    // ================= h-waves (recurrence critical path) =================
    const u64* ringu = reinterpret_cast<const u64*>(hout);
    unsigned* myflag = flags + (((w - 4) * 128 + nb) * 32);

    for (int t = 0; t < SEQ; ++t) {
      lds_wait_u(&xseq[rt], (unsigned)(t + 1));   // x buf for step t ready
      const int bn = t & 1;
      f32x4 acc[2][4];
#pragma unroll
      for (int ct = 0; ct < 2; ++ct) {
        acc[ct][0] = f32x4{x_lds[bn][rt][ct * 4 + 0][l], x_lds[bn][rt][ct * 4 + 1][l],
                           x_lds[bn][rt][ct * 4 + 2][l], x_lds[bn][rt][ct * 4 + 3][l]};
        acc[ct][1] = f32x4{0.f, 0.f, 0.f, 0.f};
        acc[ct][2] = f32x4{0.f, 0.f, 0.f, 0.f};
        acc[ct][3] = f32x4{0.f, 0.f, 0.f, 0.f};
      }
      seq_pub(&hseq[rt], (unsigned)(t + 1), l);   // buffer consumed

      if (t > 0) {
        // canary matmul: h_{t-1} @ Wh, poison-checked, 2 halves overlapped
        const u64* rowp = ringu + (size_t)((t - 1) & 511) * 16384
                          + (size_t)(rt * 16 + lr) * 256 + lq * 2;
        u64 qa[32], qb[32];
#pragma unroll
        for (int j = 0; j < 16; ++j) {
          qa[2 * j]     = gld(rowp + j * 8);
          qa[2 * j + 1] = gld(rowp + j * 8 + 1);
        }
#pragma unroll
        for (int j = 0; j < 16; ++j) {
          qb[2 * j]     = gld(rowp + (16 + j) * 8);
          qb[2 * j + 1] = gld(rowp + (16 + j) * 8 + 1);
        }
        auto CHK = [&](u64* q, int base) {
          long sp = 0;
          for (;;) {
            unsigned bad = 0;
#pragma unroll
            for (int m = 0; m < 32; ++m)
              bad |= ((unsigned)q[m] == 0xFFFFFFFFu) | ((unsigned)(q[m] >> 32) == 0xFFFFFFFFu);
            if (!__any(bad != 0)) break;
            if (++sp > 60000L) break;   // bailout
#pragma unroll
            for (int m = 0; m < 32; ++m) {
              if (((unsigned)q[m] == 0xFFFFFFFFu) | ((unsigned)(q[m] >> 32) == 0xFFFFFFFFu))
                q[m] = gld(rowp + (base + (m >> 1)) * 8 + (m & 1));
            }
          }
        };
        auto MM16 = [&](u64* q, int base) {
#pragma unroll
          for (int j = 0; j < 16; ++j) {
            int ks = base + j;
            union { u64 qq[2]; bf16x8 v; } u;
            u.qq[0] = q[2 * j]; u.qq[1] = q[2 * j + 1];
            bf16x8 bb0 = *reinterpret_cast<const bf16x8*>(wbase + ((cb0 + 2048 + ks * 64) ^ csw));
            bf16x8 bb1 = *reinterpret_cast<const bf16x8*>(wbase + ((cb1 + 2048 + ks * 64) ^ csw));
            acc[0][ks & 3] = __builtin_amdgcn_mfma_f32_16x16x32_bf16(u.v, bb0, acc[0][ks & 3], 0, 0, 0);
            acc[1][ks & 3] = __builtin_amdgcn_mfma_f32_16x16x32_bf16(u.v, bb1, acc[1][ks & 3], 0, 0, 0);
          }
        };
        CHK(qa, 0);  MM16(qa, 0);
        CHK(qb, 16); MM16(qb, 16);
      }

      // ---- in-register epilogue (r5-validated mapping) ----
      f32x4 s0 = (acc[0][0] + acc[0][1]) + (acc[0][2] + acc[0][3]);
      f32x4 s1 = (acc[1][0] + acc[1][1]) + (acc[1][2] + acc[1][3]);
      float a0[4] = {s0.x, s0.y, s0.z, s0.w};   // tile0: i (lr<8) / f (lr>=8)
      float a1[4] = {s1.x, s1.y, s1.z, s1.w};   // tile1: g (lr<8) / o (lr>=8)
      float b0r[4], b1r[4];
#pragma unroll
      for (int r = 0; r < 4; ++r) {
        b0r[r] = __shfl_xor(a0[r], 8, 64);
        b1r[r] = __shfl_xor(a1[r], 8, 64);
      }
      const bool isX = ((l & 8) == 0);
      float hvf[4];
#pragma unroll
      for (int r = 0; r < 4; ++r) {
        float gi = isX ? a0[r] : b0r[r];
        float gf = isX ? b0r[r] : a0[r];
        float gg = isX ? a1[r] : b1r[r];
        float go = isX ? b1r[r] : a1[r];
        float ig = 1.f / (1.f + __expf(-gi));
        float fg = 1.f / (1.f + __expf(-gf));
        float e2 = __expf(2.f * gg);
        float gv = (e2 - 1.f) / (e2 + 1.f);
        float og = 1.f / (1.f + __expf(-go));
        cst[r] = fg * cst[r] + ig * gv;
        float e2c = __expf(2.f * cst[r]);
        hvf[r] = og * (e2c - 1.f) / (e2c + 1.f);
      }
      float hn[4];
#pragma unroll
      for (int r = 0; r < 4; ++r) hn[r] = __shfl_xor(hvf[r], 1, 64);
      const bool ev = ((l & 1) == 0);
      unsigned pk[4]; float he[4], ho[4];
#pragma unroll
      for (int r = 0; r < 4; ++r) {
        he[r] = ev ? hvf[r] : hn[r];
        ho[r] = ev ? hn[r] : hvf[r];
        pk[r] = (unsigned)f2b(he[r]) | ((unsigned)f2b(ho[r]) << 16);
      }
      const int sub = ((l >> 3) & 1) * 2 + (l & 1);
      unsigned pks = sub == 0 ? pk[0] : sub == 1 ? pk[1] : sub == 2 ? pk[2] : pk[3];
      const int row = rt * 16 + lq * 4 + sub;
      const int cp  = (lr & 7) >> 1;
      unsigned* hw = reinterpret_cast<unsigned*>(hout + (size_t)(t & 511) * (64 * HID))
                     + (size_t)row * 512 + nb * 4 + cp;
      __hip_atomic_store(hw, pks, __ATOMIC_RELAXED, __HIP_MEMORY_SCOPE_AGENT);
      // publish IS the store: no drain, no flag on the critical path.

      // lazy flag for L1's x-waves (claims h1[t-1]; safe by in-order vmcnt:
      // this step's canary load-waits retired step t-1's stores first)
      if (layer == 0 && l == 0)
        __hip_atomic_store(myflag, (unsigned)t, __ATOMIC_RELAXED, __HIP_MEMORY_SCOPE_AGENT);

      // final output (write-once stream, nt, fire-and-forget)
      if (fout) {
        float hes = sub == 0 ? he[0] : sub == 1 ? he[1] : sub == 2 ? he[2] : he[3];
        float hos = sub == 0 ? ho[0] : sub == 1 ? ho[1] : sub == 2 ? ho[2] : ho[3];
        f32x2 o2; o2.x = hes; o2.y = hos;
        __builtin_nontemporal_store(o2,
            reinterpret_cast<f32x2*>(fout + (size_t)row * (SEQ * HID) + (size_t)t * HID
                                     + nb * 8 + cp * 2));
      }
    }
  }
}

extern "C" void kernel_launch(void* const* d_in, const int* in_sizes, int n_in,
                              void* d_out, int out_size, void* d_ws, size_t ws_size,
                              hipStream_t stream) {
  const float* x   = (const float*)d_in[0];
  const float* Wx0 = (const float*)d_in[1];
  const float* Wh0 = (const float*)d_in[2];
  const float* b0  = (const float*)d_in[3];
  const float* Wx1 = (const float*)d_in[4];
  const float* Wh1 = (const float*)d_in[5];
  const float* b1  = (const float*)d_in[6];
  float* out = (float*)d_out;
  char* ws = (char*)d_ws;

  unsigned short* xb   = (unsigned short*)(ws);                  // 64 MB @ 0
  unsigned short* h1   = (unsigned short*)(ws + 67108864);       // 64 MB
  unsigned short* h2   = (unsigned short*)(ws + 134217728);      // 64 MB
  unsigned short* WxT0 = (unsigned short*)(ws + 201326592);      // 8 MB each
  unsigned short* WhT0 = (unsigned short*)(ws + 209715200);
  unsigned short* WxT1 = (unsigned short*)(ws + 218103808);
  unsigned short* WhT1 = (unsigned short*)(ws + 226492416);
  unsigned* flags      = (unsigned*)(ws + 234881024);            // 64 KB

  // poison rings + clear flags each call (replay-safe)
  (void)hipMemsetAsync(h1, 0xFF, 67108864, stream);
  (void)hipMemsetAsync(h2, 0xFF, 67108864, stream);
  (void)hipMemsetAsync(flags, 0, 65536, stream);
  k_castx<<<32768, 256, 0, stream>>>(x, xb);
  k_wtrans<<<4096, 256, 0, stream>>>(Wx0, WxT0);
  k_wtrans<<<4096, 256, 0, stream>>>(Wh0, WhT0);
  k_wtrans<<<4096, 256, 0, stream>>>(Wx1, WxT1);
  k_wtrans<<<4096, 256, 0, stream>>>(Wh1, WhT1);
  k_scan2<<<2 * NBLK, 512, 0, stream>>>(xb, WxT0, WhT0, b0, WxT1, WhT1, b1,
                                        h1, h2, out, flags);
}

// Round 13
// 5429.285 us; speedup vs baseline: 160.1855x; 160.1855x over previous
//
#include <hip/hip_runtime.h>
#include <hip/hip_bf16.h>

#define SEQ  512
#define HID  1024
#define G4   4096
#define NBLK 128   // blocks per layer; grid = 256

typedef short bf16x8 __attribute__((ext_vector_type(8)));
typedef float f32x4  __attribute__((ext_vector_type(4)));
typedef float f32x2  __attribute__((ext_vector_type(2)));
typedef unsigned long long u64;

static __device__ __forceinline__ unsigned short f2b(float f) {
  union { float f; unsigned u; } v; v.f = f;
  unsigned r = (v.u + 0x7FFFu + ((v.u >> 16) & 1u)) >> 16;  // RNE
  return (unsigned short)r;
}
static __device__ __forceinline__ float b2f_lo(unsigned u) {
  union { unsigned u; float f; } v; v.u = u << 16; return v.f;
}
static __device__ __forceinline__ float b2f_hi(unsigned u) {
  union { unsigned u; float f; } v; v.u = u & 0xFFFF0000u; return v.f;
}

// x (B,S,I) f32 -> xb row-major (S*B, I) bf16, row r = s*64+b
__global__ __launch_bounds__(256) void k_castx(const float* __restrict__ x,
                                               unsigned short* __restrict__ xb) {
  int idx = blockIdx.x * 256 + threadIdx.x;
  int r = idx >> 8, kq = idx & 255;
  int b = r & 63, s = r >> 6;
  float4 v = *reinterpret_cast<const float4*>(x + ((size_t)b * SEQ + s) * HID + (size_t)kq * 4);
  ushort4 o;
  o.x = f2b(v.x); o.y = f2b(v.y); o.z = f2b(v.z); o.w = f2b(v.w);
  *reinterpret_cast<ushort4*>(xb + (size_t)r * HID + kq * 4) = o;
}

// W (K=1024, N=4096) f32 -> WT (N=4096, K=1024) bf16
__global__ __launch_bounds__(256) void k_wtrans(const float* __restrict__ W,
                                                unsigned short* __restrict__ WT) {
  __shared__ float tls[32][33];
  int tile = blockIdx.x;
  int nt = tile & 127, kt = tile >> 7;
  int tx = threadIdx.x & 31, ty = threadIdx.x >> 5;
  int k0 = kt * 32, n0 = nt * 32;
  for (int i = 0; i < 4; ++i)
    tls[ty + 8 * i][tx] = W[(size_t)(k0 + ty + 8 * i) * G4 + n0 + tx];
  __syncthreads();
  for (int i = 0; i < 4; ++i)
    WT[(size_t)(n0 + ty + 8 * i) * HID + k0 + tx] = f2b(tls[tx][ty + 8 * i]);
}

// Poll 128 per-block flag words (128B apart, single-writer each, no RMW).
static __device__ __forceinline__ void poll_flags128(unsigned* flags, unsigned tgt) {
  const int l = threadIdx.x & 63;
  unsigned* p0 = flags + l * 32;
  unsigned* p1 = flags + (64 + l) * 32;
  long sp = 0;
  for (;;) {
    unsigned v0 = __hip_atomic_load(p0, __ATOMIC_RELAXED, __HIP_MEMORY_SCOPE_AGENT);
    unsigned v1 = __hip_atomic_load(p1, __ATOMIC_RELAXED, __HIP_MEMORY_SCOPE_AGENT);
    if (__all((v0 >= tgt) && (v1 >= tgt))) break;
    if (++sp > 2000000L) break;   // bailout: wrong answer beats a hang
    __builtin_amdgcn_s_sleep(1);
  }
  asm volatile("" ::: "memory");
}

// r13 = r5 skeleton (best measured: 4.79 ms) + two deltas:
//  (1) fout on L1 x-waves, issued FIRST each iteration (store latency hides
//      under projection MFMAs; h-wave drain = one 4B store only)
//  (2) no relays: all consumer waves poll flags directly; last-arriving
//      h-wave publishes the block flag.
__global__ __launch_bounds__(512, 1) void k_scan2(
    const unsigned short* __restrict__ xb,
    const unsigned short* __restrict__ WxT0, const unsigned short* __restrict__ WhT0,
    const float* __restrict__ b0,
    const unsigned short* __restrict__ WxT1, const unsigned short* __restrict__ WhT1,
    const float* __restrict__ b1,
    unsigned short* __restrict__ h1,
    unsigned short* __restrict__ h2, int h2mod,
    float* __restrict__ out,
    unsigned* __restrict__ bars) {
  __shared__ unsigned short wlds[32 * 2048];   // 128 KB weights [c][k], swizzled
  __shared__ float x_lds[2][4][8][64];         // x-partials in raw MFMA layout
  __shared__ unsigned lds_arr;                 // h-wave arrivals (monotonic)

  const int bk  = blockIdx.x;
  const int layer = bk >> 7;
  const int nb  = bk & 127;
  const int tid = threadIdx.x;
  const int w   = tid >> 6;
  const int l   = tid & 63;
  const int lq  = l >> 4, lr = l & 15;
  const int rt  = w & 3;
  const bool is_h = (w >= 4);

  const unsigned short* WxT = layer ? WxT1 : WxT0;
  const unsigned short* WhT = layer ? WhT1 : WhT0;
  const float* bias = layer ? b1 : b0;
  const unsigned short* aseq = layer ? h1 : xb;
  unsigned short* hout = layer ? h2 : h1;
  const int hmod = layer ? h2mod : 512;
  float* fout = layer ? out : nullptr;
  unsigned* ownflags = bars + layer * 4096;    // my layer's 128 flag words
  unsigned* l0flags  = bars;                   // layer0 flags
  unsigned* myflag   = ownflags + nb * 32;     // this block's word (128B apart)

  if (tid == 0) lds_arr = 0;

  // ---- one-time: stage weight slice into LDS (swizzled byte addr) ----
  {
    int c = tid >> 4, seg = tid & 15;
    int gate = c >> 3, nl = c & 7;
    int gcol = gate * 1024 + nb * 8 + nl;
    const unsigned short* sx = WxT + (size_t)gcol * HID;
    const unsigned short* sh = WhT + (size_t)gcol * HID;
    for (int j = 0; j < 16; ++j) {
      int kk = seg * 128 + j * 8;
      const unsigned short* src = (kk < 1024) ? (sx + kk) : (sh + kk - 1024);
      uint4 v = *reinterpret_cast<const uint4*>(src);
      int db = (c * 4096 + kk * 2) ^ ((c & 7) << 4);
      *reinterpret_cast<uint4*>(reinterpret_cast<char*>(wlds) + db) = v;
    }
  }

  char* wbase = reinterpret_cast<char*>(wlds);
  const int csw = (lr & 7) << 4;
  const int cb0 = (lr) * 4096 + lq * 16;
  const int cb1 = (16 + lr) * 4096 + lq * 16;

  float bias_c[2];
#pragma unroll
  for (int ct = 0; ct < 2; ++ct) {
    int col = ct * 16 + lr;
    bias_c[ct] = bias[(col >> 3) * 1024 + nb * 8 + (col & 7)];
  }

  float cst[4] = {0.f, 0.f, 0.f, 0.f};   // c-state: 4 rows x 1 col per lane

  __syncthreads();
  if (is_h) __builtin_amdgcn_s_setprio(1);

  // ---- prologue: x-projection for step 0 into x_lds[0] ----
  if (!is_h) {
    if (layer) poll_flags128(l0flags, 1u);       // h1[0] complete
    const bf16x8* ax = reinterpret_cast<const bf16x8*>(aseq) + (size_t)(rt * 16 + lr) * 128 + lq;
    f32x4 acc[2][4] = {};
#pragma unroll 8
    for (int ks = 0; ks < 32; ++ks) {
      bf16x8 a  = ax[ks * 4];
      bf16x8 bb0 = *reinterpret_cast<const bf16x8*>(wbase + ((cb0 + ks * 64) ^ csw));
      bf16x8 bb1 = *reinterpret_cast<const bf16x8*>(wbase + ((cb1 + ks * 64) ^ csw));
      acc[0][ks & 3] = __builtin_amdgcn_mfma_f32_16x16x32_bf16(a, bb0, acc[0][ks & 3], 0, 0, 0);
      acc[1][ks & 3] = __builtin_amdgcn_mfma_f32_16x16x32_bf16(a, bb1, acc[1][ks & 3], 0, 0, 0);
    }
#pragma unroll
    for (int ct = 0; ct < 2; ++ct) {
      f32x4 s = (acc[ct][0] + acc[ct][1]) + (acc[ct][2] + acc[ct][3]);
      float bc = bias_c[ct];
      x_lds[0][w][ct * 4 + 0][l] = s.x + bc;
      x_lds[0][w][ct * 4 + 1][l] = s.y + bc;
      x_lds[0][w][ct * 4 + 2][l] = s.z + bc;
      x_lds[0][w][ct * 4 + 3][l] = s.w + bc;
    }
  }
  __syncthreads();

  for (int t = 0; t < SEQ; ++t) {
    if (!is_h) {
      // ---------- (1) L1 x-waves: copy own-block cols of h2[t-1] -> fout ----------
      // Issued FIRST: stores retire under the projection MFMAs below.
      // Safe: prior iteration's barrier guarantees h2[t-1] drained to L3.
      if (fout && t > 0) {
        const unsigned* sp32 = reinterpret_cast<const unsigned*>(
            hout + (size_t)((t - 1) % hmod) * (64 * HID)) + (size_t)l * 512 + nb * 4 + rt;
        unsigned pv = __hip_atomic_load(sp32, __ATOMIC_RELAXED, __HIP_MEMORY_SCOPE_AGENT);
        f32x2 o2; o2.x = b2f_lo(pv); o2.y = b2f_hi(pv);
        __builtin_nontemporal_store(o2,
            reinterpret_cast<f32x2*>(fout + (size_t)l * (SEQ * HID) + (size_t)(t - 1) * HID
                                     + nb * 8 + rt * 2));
      }
      // ---------- x-waves: project input of step t+1 into x_lds[(t+1)&1] ----------
      if (t + 1 < SEQ) {
        if (layer) poll_flags128(l0flags, (unsigned)(t + 2));   // h1[t+1] complete
        const bf16x8* ax = reinterpret_cast<const bf16x8*>(aseq)
                           + ((size_t)(t + 1) * 64 + rt * 16 + lr) * 128 + lq;
        f32x4 acc[2][4] = {};
#pragma unroll 8
        for (int ks = 0; ks < 32; ++ks) {
          bf16x8 a  = ax[ks * 4];
          bf16x8 bb0 = *reinterpret_cast<const bf16x8*>(wbase + ((cb0 + ks * 64) ^ csw));
          bf16x8 bb1 = *reinterpret_cast<const bf16x8*>(wbase + ((cb1 + ks * 64) ^ csw));
          acc[0][ks & 3] = __builtin_amdgcn_mfma_f32_16x16x32_bf16(a, bb0, acc[0][ks & 3], 0, 0, 0);
          acc[1][ks & 3] = __builtin_amdgcn_mfma_f32_16x16x32_bf16(a, bb1, acc[1][ks & 3], 0, 0, 0);
        }
        int bn2 = (t + 1) & 1;
#pragma unroll
        for (int ct = 0; ct < 2; ++ct) {
          f32x4 s = (acc[ct][0] + acc[ct][1]) + (acc[ct][2] + acc[ct][3]);
          float bc = bias_c[ct];
          x_lds[bn2][w][ct * 4 + 0][l] = s.x + bc;
          x_lds[bn2][w][ct * 4 + 1][l] = s.y + bc;
          x_lds[bn2][w][ct * 4 + 2][l] = s.z + bc;
          x_lds[bn2][w][ct * 4 + 3][l] = s.w + bc;
        }
      }
    } else {
      // ---------- h-waves: recurrence critical path ----------
      const int bn = t & 1;
      f32x4 acc[2][4];
#pragma unroll
      for (int ct = 0; ct < 2; ++ct) {
        acc[ct][0] = f32x4{x_lds[bn][rt][ct * 4 + 0][l], x_lds[bn][rt][ct * 4 + 1][l],
                           x_lds[bn][rt][ct * 4 + 2][l], x_lds[bn][rt][ct * 4 + 3][l]};
        acc[ct][1] = f32x4{0.f, 0.f, 0.f, 0.f};
        acc[ct][2] = f32x4{0.f, 0.f, 0.f, 0.f};
        acc[ct][3] = f32x4{0.f, 0.f, 0.f, 0.f};
      }

      if (t > 0) {
        poll_flags128(ownflags, (unsigned)t);   // (2) all h-waves poll directly
        const size_t hbase = (size_t)((t - 1) % hmod) * (64 * HID) + (size_t)(rt * 16 + lr) * HID;
        if (hmod != 4) {
          const bf16x8* hp = reinterpret_cast<const bf16x8*>(hout + hbase) + lq;
#pragma unroll 8
          for (int ks = 0; ks < 32; ++ks) {
            bf16x8 a = hp[ks * 4];
            bf16x8 bb0 = *reinterpret_cast<const bf16x8*>(wbase + ((cb0 + 2048 + ks * 64) ^ csw));
            bf16x8 bb1 = *reinterpret_cast<const bf16x8*>(wbase + ((cb1 + 2048 + ks * 64) ^ csw));
            acc[0][ks & 3] = __builtin_amdgcn_mfma_f32_16x16x32_bf16(a, bb0, acc[0][ks & 3], 0, 0, 0);
            acc[1][ks & 3] = __builtin_amdgcn_mfma_f32_16x16x32_bf16(a, bb1, acc[1][ks & 3], 0, 0, 0);
          }
        } else {
          const u64* hp = reinterpret_cast<const u64*>(hout + hbase) + lq * 2;
#pragma unroll 8
          for (int ks = 0; ks < 32; ++ks) {
            u64 q0 = __hip_atomic_load(hp + ks * 8,     __ATOMIC_RELAXED, __HIP_MEMORY_SCOPE_AGENT);
            u64 q1 = __hip_atomic_load(hp + ks * 8 + 1, __ATOMIC_RELAXED, __HIP_MEMORY_SCOPE_AGENT);
            union { u64 q[2]; bf16x8 v; } u; u.q[0] = q0; u.q[1] = q1;
            bf16x8 bb0 = *reinterpret_cast<const bf16x8*>(wbase + ((cb0 + 2048 + ks * 64) ^ csw));
            bf16x8 bb1 = *reinterpret_cast<const bf16x8*>(wbase + ((cb1 + 2048 + ks * 64) ^ csw));
            acc[0][ks & 3] = __builtin_amdgcn_mfma_f32_16x16x32_bf16(u.v, bb0, acc[0][ks & 3], 0, 0, 0);
            acc[1][ks & 3] = __builtin_amdgcn_mfma_f32_16x16x32_bf16(u.v, bb1, acc[1][ks & 3], 0, 0, 0);
          }
        }
      }

      // ---- in-register epilogue (r5-validated mapping) ----
      f32x4 s0 = (acc[0][0] + acc[0][1]) + (acc[0][2] + acc[0][3]);
      f32x4 s1 = (acc[1][0] + acc[1][1]) + (acc[1][2] + acc[1][3]);
      float a0[4] = {s0.x, s0.y, s0.z, s0.w};   // tile0: i (lr<8) / f (lr>=8)
      float a1[4] = {s1.x, s1.y, s1.z, s1.w};   // tile1: g (lr<8) / o (lr>=8)
      float b0r[4], b1r[4];
#pragma unroll
      for (int r = 0; r < 4; ++r) {
        b0r[r] = __shfl_xor(a0[r], 8, 64);
        b1r[r] = __shfl_xor(a1[r], 8, 64);
      }
      const bool isX = ((l & 8) == 0);
      float hvf[4];
#pragma unroll
      for (int r = 0; r < 4; ++r) {
        float gi = isX ? a0[r] : b0r[r];
        float gf = isX ? b0r[r] : a0[r];
        float gg = isX ? a1[r] : b1r[r];
        float go = isX ? b1r[r] : a1[r];
        float ig = 1.f / (1.f + __expf(-gi));
        float fg = 1.f / (1.f + __expf(-gf));
        float e2 = __expf(2.f * gg);
        float gv = (e2 - 1.f) / (e2 + 1.f);
        float og = 1.f / (1.f + __expf(-go));
        cst[r] = fg * cst[r] + ig * gv;
        float e2c = __expf(2.f * cst[r]);
        hvf[r] = og * (e2c - 1.f) / (e2c + 1.f);
      }
      // col-pair packing: lane^1 exchange, then one u32 store per lane
      float hn[4];
#pragma unroll
      for (int r = 0; r < 4; ++r) hn[r] = __shfl_xor(hvf[r], 1, 64);
      const bool ev = ((l & 1) == 0);
      unsigned pk[4];
#pragma unroll
      for (int r = 0; r < 4; ++r) {
        float he = ev ? hvf[r] : hn[r];
        float ho = ev ? hn[r] : hvf[r];
        pk[r] = (unsigned)f2b(he) | ((unsigned)f2b(ho) << 16);
      }
      const int sub = ((l >> 3) & 1) * 2 + (l & 1);     // 0..3: which row I store
      unsigned pks = sub == 0 ? pk[0] : sub == 1 ? pk[1] : sub == 2 ? pk[2] : pk[3];
      const int row = rt * 16 + lq * 4 + sub;
      const int cp  = (lr & 7) >> 1;
      unsigned* hw = reinterpret_cast<unsigned*>(hout + (size_t)(t % hmod) * (64 * HID))
                     + (size_t)row * 512 + nb * 4 + cp;
      __hip_atomic_store(hw, pks, __ATOMIC_RELAXED, __HIP_MEMORY_SCOPE_AGENT);

      // drain own 4B store, then last-arriving h-wave publishes the flag
      asm volatile("s_waitcnt vmcnt(0)" ::: "memory");
      if (l == 0) {
        unsigned pb = atomicAdd(&lds_arr, 1u);
        if ((pb & 3) == 3)
          __hip_atomic_store(myflag, (pb >> 2) + 1u, __ATOMIC_RELAXED,
                             __HIP_MEMORY_SCOPE_AGENT);
      }
    }
    __syncthreads();
  }

  // final output column t=511 (L1 x-waves; last barrier guaranteed h2[511])
  if (!is_h && fout) {
    const unsigned* sp32 = reinterpret_cast<const unsigned*>(
        hout + (size_t)(511 % hmod) * (64 * HID)) + (size_t)l * 512 + nb * 4 + rt;
    unsigned pv = __hip_atomic_load(sp32, __ATOMIC_RELAXED, __HIP_MEMORY_SCOPE_AGENT);
    f32x2 o2; o2.x = b2f_lo(pv); o2.y = b2f_hi(pv);
    __builtin_nontemporal_store(o2,
        reinterpret_cast<f32x2*>(fout + (size_t)l * (SEQ * HID) + (size_t)511 * HID
                                 + nb * 8 + rt * 2));
  }
}

extern "C" void kernel_launch(void* const* d_in, const int* in_sizes, int n_in,
                              void* d_out, int out_size, void* d_ws, size_t ws_size,
                              hipStream_t stream) {
  const float* x   = (const float*)d_in[0];
  const float* Wx0 = (const float*)d_in[1];
  const float* Wh0 = (const float*)d_in[2];
  const float* b0  = (const float*)d_in[3];
  const float* Wx1 = (const float*)d_in[4];
  const float* Wh1 = (const float*)d_in[5];
  const float* b1  = (const float*)d_in[6];
  float* out = (float*)d_out;
  char* ws = (char*)d_ws;

  unsigned short* xb   = (unsigned short*)(ws);                  // 64 MB
  unsigned short* h1   = (unsigned short*)(ws + 67108864);       // 64 MB
  unsigned short* WxT0 = (unsigned short*)(ws + 134217728);      // 8 MB each
  unsigned short* WhT0 = (unsigned short*)(ws + 142606336);
  unsigned short* WxT1 = (unsigned short*)(ws + 150994944);
  unsigned short* WhT1 = (unsigned short*)(ws + 159383552);
  unsigned* bars       = (unsigned*)(ws + 167772160);            // 32 KB flags
  unsigned short* h2   = (unsigned short*)(ws + 167804928);
  int h2mod = (ws_size >= (size_t)167804928 + 67108864) ? 512 : 4;

  (void)hipMemsetAsync(bars, 0, 32768, stream);
  k_castx<<<32768, 256, 0, stream>>>(x, xb);
  k_wtrans<<<4096, 256, 0, stream>>>(Wx0, WxT0);
  k_wtrans<<<4096, 256, 0, stream>>>(Wh0, WhT0);
  k_wtrans<<<4096, 256, 0, stream>>>(Wx1, WxT1);
  k_wtrans<<<4096, 256, 0, stream>>>(Wh1, WhT1);
  k_scan2<<<2 * NBLK, 512, 0, stream>>>(xb, WxT0, WhT0, b0, WxT1, WhT1, b1,
                                        h1, h2, h2mod, out, bars);
}